// Round 1
// baseline (262.409 us; speedup 1.0000x reference)
//
#include <hip/hip_runtime.h>
#include <hip/hip_bf16.h>
#include <stdint.h>

#define T_TOK 2048
#define H_DIM 1024
#define E_NUM 8
#define I_DIM 512
#define KDOWN (E_NUM * I_DIM) /* 4096 */
#define EPSR 1e-8f

typedef short s16x8 __attribute__((ext_vector_type(8)));
typedef float f32x4 __attribute__((ext_vector_type(4)));

static __device__ __forceinline__ uint16_t f2bf(float f) {
    union { float f; uint32_t i; } v; v.f = f;
    uint32_t lsb = (v.i >> 16) & 1u;
    v.i += 0x7fffu + lsb;                    // round-to-nearest-even
    return (uint16_t)(v.i >> 16);
}

// ---------------- cast x (fp32 -> bf16), 4 elems/thread ----------------
__global__ __launch_bounds__(256) void cast_x_kernel(const float* __restrict__ x,
                                                     uint16_t* __restrict__ xb) {
    int i = (blockIdx.x * 256 + threadIdx.x) * 4;
    float4 v = *(const float4*)(x + i);
    ushort4 o;
    o.x = f2bf(v.x); o.y = f2bf(v.y); o.z = f2bf(v.z); o.w = f2bf(v.w);
    *(ushort4*)(xb + i) = o;
}

// ------------- transpose + cast: in[R][C] fp32 -> out[c*stride + r] bf16 -------------
// grid (C/32, R/32, E), block (32,8)
__global__ __launch_bounds__(256) void transpose_cast_kernel(
    const float* __restrict__ in, uint16_t* __restrict__ out,
    int R, int C, long in_batch, long out_batch, int out_stride) {
    __shared__ float tile[32][33];
    const float* src = in + (long)blockIdx.z * in_batch;
    uint16_t* dst = out + (long)blockIdx.z * out_batch;
    int c0 = blockIdx.x * 32, r0 = blockIdx.y * 32;
    for (int rr = threadIdx.y; rr < 32; rr += 8)
        tile[rr][threadIdx.x] = src[(long)(r0 + rr) * C + c0 + threadIdx.x];
    __syncthreads();
    for (int cc = threadIdx.y; cc < 32; cc += 8)
        dst[(long)(c0 + cc) * out_stride + r0 + threadIdx.x] = f2bf(tile[threadIdx.x][cc]);
}

// ---------------- routing: cosine scores + masked softmax gates ----------------
// one wave per token; grid 512 blocks x 256 threads
__global__ __launch_bounds__(256) void routing_kernel(
    const float* __restrict__ x, const float* __restrict__ emb,
    const float* __restrict__ thr, float* __restrict__ scores_out,
    float* __restrict__ gates) {
    __shared__ float semb[E_NUM * H_DIM];
    __shared__ float senorm[E_NUM];
    const int tid = threadIdx.x;
    const int lane = tid & 63;
    const int wave = tid >> 6;
    for (int i = tid; i < E_NUM * H_DIM; i += 256) semb[i] = emb[i];
    __syncthreads();
    for (int e = wave; e < E_NUM; e += 4) {
        float s = 0.f;
        #pragma unroll
        for (int c = 0; c < 16; ++c) { float v = semb[e * H_DIM + lane + 64 * c]; s += v * v; }
        #pragma unroll
        for (int off = 32; off; off >>= 1) s += __shfl_xor(s, off);
        if (lane == 0) senorm[e] = fmaxf(sqrtf(s), EPSR);
    }
    __syncthreads();
    const int t = blockIdx.x * 4 + wave;
    const float* xt = x + (long)t * H_DIM;
    float nrm = 0.f, dot[E_NUM];
    #pragma unroll
    for (int e = 0; e < E_NUM; ++e) dot[e] = 0.f;
    #pragma unroll
    for (int c = 0; c < 16; ++c) {
        float v = xt[lane + 64 * c];
        nrm += v * v;
        #pragma unroll
        for (int e = 0; e < E_NUM; ++e) dot[e] += v * semb[e * H_DIM + lane + 64 * c];
    }
    #pragma unroll
    for (int off = 32; off; off >>= 1) {
        nrm += __shfl_xor(nrm, off);
        #pragma unroll
        for (int e = 0; e < E_NUM; ++e) dot[e] += __shfl_xor(dot[e], off);
    }
    float xn = fmaxf(sqrtf(nrm), EPSR);
    float sc[E_NUM], sel[E_NUM];
    float msel = -1e30f, mall = -1e30f;
    int nsel = 0, arg = 0;
    #pragma unroll
    for (int e = 0; e < E_NUM; ++e) {
        sc[e] = dot[e] / (xn * senorm[e]);
        float d = sc[e] - thr[e];
        sel[e] = (d > 0.f) ? 1.f : 0.f;                 // silu(d) > 0  <=>  d > 0
        if (d > 0.f) { nsel++; msel = fmaxf(msel, sc[e]); }
        if (sc[e] > mall) { mall = sc[e]; arg = e; }    // first-index argmax via strict >
    }
    float w[E_NUM], den = 0.f;
    #pragma unroll
    for (int e = 0; e < E_NUM; ++e) { w[e] = (sel[e] > 0.f) ? __expf(sc[e] - msel) : 0.f; den += w[e]; }
    if (lane == 0) {
        #pragma unroll
        for (int e = 0; e < E_NUM; ++e) {
            scores_out[t * E_NUM + e] = sc[e];
            gates[t * E_NUM + e] = (nsel > 0) ? (w[e] / den) : ((e == arg) ? 1.f : 0.f);
        }
    }
}

// ---------------- gate/up GEMM + silu*up*gate -> Hmid bf16 ----------------
// grid (T/128, I/128, E) = (16,4,8); block 256 (4 waves, 2x2); BK=32
__global__ __launch_bounds__(256) void moe_gateup_kernel(
    const uint16_t* __restrict__ xb,    // [2048][1024]
    const uint16_t* __restrict__ wgT,   // [8][512][1024]
    const uint16_t* __restrict__ wuT,   // [8][512][1024]
    const float* __restrict__ gates,    // [2048][8]
    uint16_t* __restrict__ hmid) {      // [2048][4096] = [t][e*512+i]
    const int e  = blockIdx.z;
    const int t0 = blockIdx.x * 128;
    const int i0 = blockIdx.y * 128;
    __shared__ uint16_t sA[128][40];
    __shared__ uint16_t sG[128][40];
    __shared__ uint16_t sU[128][40];
    __shared__ float sGate[128];
    const int tid  = threadIdx.x;
    const int lane = tid & 63;
    const int wave = tid >> 6;
    const int wm = wave >> 1, wn = wave & 1;
    if (tid < 128) sGate[tid] = gates[(t0 + tid) * E_NUM + e];

    const uint16_t* aptr = xb  + (long)t0 * H_DIM;
    const uint16_t* gptr = wgT + ((long)e * I_DIM + i0) * H_DIM;
    const uint16_t* uptr = wuT + ((long)e * I_DIM + i0) * H_DIM;
    // staging assignment: chunk c = tid + 256*r -> row c>>2, k-offset (c&3)*8
    const int row0 = tid >> 2,          kc0 = (tid & 3) * 8;
    const int row1 = (tid + 256) >> 2,  kc1 = (tid & 3) * 8;   // (tid+256)&3 == tid&3

    f32x4 accg[4][4] = {};
    f32x4 accu[4][4] = {};
    const int q = lane >> 4, r16 = lane & 15;

    for (int kb = 0; kb < H_DIM; kb += 32) {
        __syncthreads();
        *(uint4*)&sA[row0][kc0] = *(const uint4*)(aptr + (long)row0 * H_DIM + kb + kc0);
        *(uint4*)&sA[row1][kc1] = *(const uint4*)(aptr + (long)row1 * H_DIM + kb + kc1);
        *(uint4*)&sG[row0][kc0] = *(const uint4*)(gptr + (long)row0 * H_DIM + kb + kc0);
        *(uint4*)&sG[row1][kc1] = *(const uint4*)(gptr + (long)row1 * H_DIM + kb + kc1);
        *(uint4*)&sU[row0][kc0] = *(const uint4*)(uptr + (long)row0 * H_DIM + kb + kc0);
        *(uint4*)&sU[row1][kc1] = *(const uint4*)(uptr + (long)row1 * H_DIM + kb + kc1);
        __syncthreads();
        s16x8 af[4], gf[4], uf[4];
        #pragma unroll
        for (int m = 0; m < 4; ++m)
            af[m] = *(const s16x8*)&sA[wm * 64 + m * 16 + r16][q * 8];
        #pragma unroll
        for (int n = 0; n < 4; ++n) {
            gf[n] = *(const s16x8*)&sG[wn * 64 + n * 16 + r16][q * 8];
            uf[n] = *(const s16x8*)&sU[wn * 64 + n * 16 + r16][q * 8];
        }
        #pragma unroll
        for (int m = 0; m < 4; ++m)
            #pragma unroll
            for (int n = 0; n < 4; ++n) {
                accg[m][n] = __builtin_amdgcn_mfma_f32_16x16x32_bf16(af[m], gf[n], accg[m][n], 0, 0, 0);
                accu[m][n] = __builtin_amdgcn_mfma_f32_16x16x32_bf16(af[m], uf[n], accu[m][n], 0, 0, 0);
            }
    }
    // epilogue: D row = q*4+rr (token), col = r16 (i)
    #pragma unroll
    for (int m = 0; m < 4; ++m) {
        #pragma unroll
        for (int rr = 0; rr < 4; ++rr) {
            int trow = wm * 64 + m * 16 + q * 4 + rr;
            float gate = sGate[trow];
            long base = (long)(t0 + trow) * KDOWN + e * I_DIM;
            #pragma unroll
            for (int n = 0; n < 4; ++n) {
                int icol = i0 + wn * 64 + n * 16 + r16;
                float g = accg[m][n][rr], u = accu[m][n][rr];
                float h = gate * (g / (1.f + __expf(-g))) * u;
                hmid[base + icol] = f2bf(h);
            }
        }
    }
}

// ---------------- down GEMM: out[t][h] += Hmid[t][:] @ WdT[h][:] ----------------
// grid (T/128, H/128, 4 splitK) = (16,8,4); block 256; BK=32; K-chunk 1024
__global__ __launch_bounds__(256) void moe_down_kernel(
    const uint16_t* __restrict__ hmid,  // [2048][4096]
    const uint16_t* __restrict__ wdT,   // [1024][4096]
    float* __restrict__ out) {          // [2048][1024], pre-zeroed
    const int t0 = blockIdx.x * 128;
    const int h0 = blockIdx.y * 128;
    const int k0 = blockIdx.z * 1024;
    __shared__ uint16_t sA[128][40];
    __shared__ uint16_t sB[128][40];
    const int tid  = threadIdx.x;
    const int lane = tid & 63;
    const int wave = tid >> 6;
    const int wm = wave >> 1, wn = wave & 1;
    const int row0 = tid >> 2,         kc0 = (tid & 3) * 8;
    const int row1 = (tid + 256) >> 2, kc1 = (tid & 3) * 8;
    const uint16_t* aptr = hmid + (long)t0 * KDOWN;
    const uint16_t* bptr = wdT  + (long)h0 * KDOWN;
    f32x4 acc[4][4] = {};
    const int q = lane >> 4, r16 = lane & 15;

    for (int kb = k0; kb < k0 + 1024; kb += 32) {
        __syncthreads();
        *(uint4*)&sA[row0][kc0] = *(const uint4*)(aptr + (long)row0 * KDOWN + kb + kc0);
        *(uint4*)&sA[row1][kc1] = *(const uint4*)(aptr + (long)row1 * KDOWN + kb + kc1);
        *(uint4*)&sB[row0][kc0] = *(const uint4*)(bptr + (long)row0 * KDOWN + kb + kc0);
        *(uint4*)&sB[row1][kc1] = *(const uint4*)(bptr + (long)row1 * KDOWN + kb + kc1);
        __syncthreads();
        s16x8 af[4], bf[4];
        #pragma unroll
        for (int m = 0; m < 4; ++m)
            af[m] = *(const s16x8*)&sA[wm * 64 + m * 16 + r16][q * 8];
        #pragma unroll
        for (int n = 0; n < 4; ++n)
            bf[n] = *(const s16x8*)&sB[wn * 64 + n * 16 + r16][q * 8];
        #pragma unroll
        for (int m = 0; m < 4; ++m)
            #pragma unroll
            for (int n = 0; n < 4; ++n)
                acc[m][n] = __builtin_amdgcn_mfma_f32_16x16x32_bf16(af[m], bf[n], acc[m][n], 0, 0, 0);
    }
    #pragma unroll
    for (int m = 0; m < 4; ++m) {
        #pragma unroll
        for (int rr = 0; rr < 4; ++rr) {
            int t = t0 + wm * 64 + m * 16 + q * 4 + rr;
            #pragma unroll
            for (int n = 0; n < 4; ++n) {
                int h = h0 + wn * 64 + n * 16 + r16;
                atomicAdd(&out[(long)t * H_DIM + h], acc[m][n][rr]);
            }
        }
    }
}

extern "C" void kernel_launch(void* const* d_in, const int* in_sizes, int n_in,
                              void* d_out, int out_size, void* d_ws, size_t ws_size,
                              hipStream_t stream) {
    const float* x    = (const float*)d_in[0];   // [2,1024,1024]
    const float* emb  = (const float*)d_in[1];   // [8,1024]
    const float* thr  = (const float*)d_in[2];   // [8]
    const float* wg   = (const float*)d_in[3];   // [8,1024,512]
    const float* wu   = (const float*)d_in[4];   // [8,1024,512]
    const float* wd   = (const float*)d_in[5];   // [8,512,1024]
    float* out    = (float*)d_out;               // [2048][1024]
    float* scores = out + (size_t)T_TOK * H_DIM; // [2048][8]

    uint8_t* ws = (uint8_t*)d_ws;
    uint16_t* xb   = (uint16_t*)(ws);                         //  4 MB  x bf16
    uint16_t* wgT  = (uint16_t*)(ws + (size_t)4  * 1048576);  //  8 MB  [E][I][H]
    uint16_t* wuT  = (uint16_t*)(ws + (size_t)12 * 1048576);  //  8 MB  [E][I][H]
    uint16_t* wdT  = (uint16_t*)(ws + (size_t)20 * 1048576);  //  8 MB  [H][E*I]
    uint16_t* hmid = (uint16_t*)(ws + (size_t)28 * 1048576);  // 16 MB  [T][E*I]
    float*    gates = (float*)  (ws + (size_t)44 * 1048576);  // 64 KB  [T][E]

    // zero output region (atomic accumulation target)
    hipMemsetAsync(out, 0, (size_t)T_TOK * H_DIM * sizeof(float), stream);

    cast_x_kernel<<<(T_TOK * H_DIM) / 1024, 256, 0, stream>>>(x, xb);
    // Wg [H][I] -> wgT[e][i][h]
    transpose_cast_kernel<<<dim3(I_DIM / 32, H_DIM / 32, E_NUM), dim3(32, 8), 0, stream>>>(
        wg, wgT, H_DIM, I_DIM, (long)H_DIM * I_DIM, (long)I_DIM * H_DIM, H_DIM);
    transpose_cast_kernel<<<dim3(I_DIM / 32, H_DIM / 32, E_NUM), dim3(32, 8), 0, stream>>>(
        wu, wuT, H_DIM, I_DIM, (long)H_DIM * I_DIM, (long)I_DIM * H_DIM, H_DIM);
    // Wd [I][H] -> wdT[h][e*512+i]
    transpose_cast_kernel<<<dim3(H_DIM / 32, I_DIM / 32, E_NUM), dim3(32, 8), 0, stream>>>(
        wd, wdT, I_DIM, H_DIM, (long)I_DIM * H_DIM, (long)I_DIM, KDOWN);
    routing_kernel<<<T_TOK / 4, 256, 0, stream>>>(x, emb, thr, scores, gates);
    moe_gateup_kernel<<<dim3(T_TOK / 128, I_DIM / 128, E_NUM), 256, 0, stream>>>(
        xb, wgT, wuT, gates, hmid);
    moe_down_kernel<<<dim3(T_TOK / 128, H_DIM / 128, 4), 256, 0, stream>>>(hmid, wdT, out);
}

// Round 2
// 230.636 us; speedup vs baseline: 1.1378x; 1.1378x over previous
//
#include <hip/hip_runtime.h>
#include <hip/hip_bf16.h>
#include <stdint.h>

#define T_TOK 2048
#define H_DIM 1024
#define E_NUM 8
#define I_DIM 512
#define KDOWN (E_NUM * I_DIM) /* 4096 */
#define EPSR 1e-8f

typedef short s16x8 __attribute__((ext_vector_type(8)));
typedef float f32x4 __attribute__((ext_vector_type(4)));

static __device__ __forceinline__ uint16_t f2bf(float f) {
    union { float f; uint32_t i; } v; v.f = f;
    uint32_t lsb = (v.i >> 16) & 1u;
    v.i += 0x7fffu + lsb;                    // round-to-nearest-even
    return (uint16_t)(v.i >> 16);
}

// async global->LDS DMA, 16B per lane; LDS dest = wave-uniform base + lane*16
static __device__ __forceinline__ void gll16(const void* g, void* l) {
    __builtin_amdgcn_global_load_lds(
        (const __attribute__((address_space(1))) void*)g,
        (__attribute__((address_space(3))) void*)l, 16, 0, 0);
}

// ---------------- cast x (fp32 -> bf16), 4 elems/thread ----------------
__global__ __launch_bounds__(256) void cast_x_kernel(const float* __restrict__ x,
                                                     uint16_t* __restrict__ xb) {
    int i = (blockIdx.x * 256 + threadIdx.x) * 4;
    float4 v = *(const float4*)(x + i);
    ushort4 o;
    o.x = f2bf(v.x); o.y = f2bf(v.y); o.z = f2bf(v.z); o.w = f2bf(v.w);
    *(ushort4*)(xb + i) = o;
}

// ------------- transpose + cast: in[R][C] fp32 -> out[c*stride + r] bf16 -------------
__global__ __launch_bounds__(256) void transpose_cast_kernel(
    const float* __restrict__ in, uint16_t* __restrict__ out,
    int R, int C, long in_batch, long out_batch, int out_stride) {
    __shared__ float tile[32][33];
    const float* src = in + (long)blockIdx.z * in_batch;
    uint16_t* dst = out + (long)blockIdx.z * out_batch;
    int c0 = blockIdx.x * 32, r0 = blockIdx.y * 32;
    for (int rr = threadIdx.y; rr < 32; rr += 8)
        tile[rr][threadIdx.x] = src[(long)(r0 + rr) * C + c0 + threadIdx.x];
    __syncthreads();
    for (int cc = threadIdx.y; cc < 32; cc += 8)
        dst[(long)(c0 + cc) * out_stride + r0 + threadIdx.x] = f2bf(tile[threadIdx.x][cc]);
}

// ---------------- routing: cosine scores + masked softmax gates ----------------
__global__ __launch_bounds__(256) void routing_kernel(
    const float* __restrict__ x, const float* __restrict__ emb,
    const float* __restrict__ thr, float* __restrict__ scores_out,
    float* __restrict__ gates) {
    __shared__ float semb[E_NUM * H_DIM];
    __shared__ float senorm[E_NUM];
    const int tid = threadIdx.x;
    const int lane = tid & 63;
    const int wave = tid >> 6;
    for (int i = tid; i < E_NUM * H_DIM; i += 256) semb[i] = emb[i];
    __syncthreads();
    for (int e = wave; e < E_NUM; e += 4) {
        float s = 0.f;
        #pragma unroll
        for (int c = 0; c < 16; ++c) { float v = semb[e * H_DIM + lane + 64 * c]; s += v * v; }
        #pragma unroll
        for (int off = 32; off; off >>= 1) s += __shfl_xor(s, off);
        if (lane == 0) senorm[e] = fmaxf(sqrtf(s), EPSR);
    }
    __syncthreads();
    const int t = blockIdx.x * 4 + wave;
    const float* xt = x + (long)t * H_DIM;
    float nrm = 0.f, dot[E_NUM];
    #pragma unroll
    for (int e = 0; e < E_NUM; ++e) dot[e] = 0.f;
    #pragma unroll
    for (int c = 0; c < 16; ++c) {
        float v = xt[lane + 64 * c];
        nrm += v * v;
        #pragma unroll
        for (int e = 0; e < E_NUM; ++e) dot[e] += v * semb[e * H_DIM + lane + 64 * c];
    }
    #pragma unroll
    for (int off = 32; off; off >>= 1) {
        nrm += __shfl_xor(nrm, off);
        #pragma unroll
        for (int e = 0; e < E_NUM; ++e) dot[e] += __shfl_xor(dot[e], off);
    }
    float xn = fmaxf(sqrtf(nrm), EPSR);
    float sc[E_NUM], sel[E_NUM];
    float msel = -1e30f, mall = -1e30f;
    int nsel = 0, arg = 0;
    #pragma unroll
    for (int e = 0; e < E_NUM; ++e) {
        sc[e] = dot[e] / (xn * senorm[e]);
        float d = sc[e] - thr[e];
        sel[e] = (d > 0.f) ? 1.f : 0.f;                 // silu(d) > 0  <=>  d > 0
        if (d > 0.f) { nsel++; msel = fmaxf(msel, sc[e]); }
        if (sc[e] > mall) { mall = sc[e]; arg = e; }
    }
    float w[E_NUM], den = 0.f;
    #pragma unroll
    for (int e = 0; e < E_NUM; ++e) { w[e] = (sel[e] > 0.f) ? __expf(sc[e] - msel) : 0.f; den += w[e]; }
    if (lane == 0) {
        #pragma unroll
        for (int e = 0; e < E_NUM; ++e) {
            scores_out[t * E_NUM + e] = sc[e];
            gates[t * E_NUM + e] = (nsel > 0) ? (w[e] / den) : ((e == arg) ? 1.f : 0.f);
        }
    }
}

// ---------------- gate/up GEMM + silu*up*gate -> Hmid bf16 ----------------
// grid (T/128, I/128, E) = (16,4,8); block 256 (4 waves, 2x2); BK=64
// LDS layout: [128 rows][64 k] unpadded (128B rows); chunk c (16B) of row r is
// stored at physical chunk c ^ (r&7)  -> conflict-free frag reads, and the
// global_load_lds DMA (dest = base + lane*16) stays contiguous.
__global__ __launch_bounds__(256) void moe_gateup_kernel(
    const uint16_t* __restrict__ xb,    // [2048][1024]
    const uint16_t* __restrict__ wgT,   // [8][512][1024]
    const uint16_t* __restrict__ wuT,   // [8][512][1024]
    const float* __restrict__ gates,    // [2048][8]
    uint16_t* __restrict__ hmid) {      // [2048][4096] = [t][e*512+i]
    const int e  = blockIdx.z;
    const int t0 = blockIdx.x * 128;
    const int i0 = blockIdx.y * 128;
    __shared__ uint16_t sA[128][64];
    __shared__ uint16_t sG[128][64];
    __shared__ uint16_t sU[128][64];
    __shared__ float sGate[128];
    const int tid  = threadIdx.x;
    const int lane = tid & 63;
    const int wave = tid >> 6;
    const int wm = wave >> 1, wn = wave & 1;
    if (tid < 128) sGate[tid] = gates[(t0 + tid) * E_NUM + e];

    // staging: wave w covers rows [w*32, w*32+32); 4 chunks of 8 rows per tile
    const int srow = wave * 32 + (lane >> 3);
    const int scol = ((lane & 7) ^ (srow & 7)) * 8;   // swizzled source chunk
    const uint16_t* ga = xb  + (long)(t0 + srow) * H_DIM + scol;
    const uint16_t* gg = wgT + ((long)e * I_DIM + i0 + srow) * H_DIM + scol;
    const uint16_t* gu = wuT + ((long)e * I_DIM + i0 + srow) * H_DIM + scol;

    f32x4 accg[4][4] = {};
    f32x4 accu[4][4] = {};
    const int q = lane >> 4, r16 = lane & 15;
    const int sw = r16 & 7;

    for (int kb = 0; kb < H_DIM; kb += 64) {
        __syncthreads();
        #pragma unroll
        for (int j = 0; j < 4; ++j) {
            long go = (long)j * 8 * H_DIM + kb;
            gll16(ga + go, &sA[wave * 32 + j * 8][0]);
            gll16(gg + go, &sG[wave * 32 + j * 8][0]);
            gll16(gu + go, &sU[wave * 32 + j * 8][0]);
        }
        __syncthreads();
        #pragma unroll
        for (int kk = 0; kk < 2; ++kk) {
            s16x8 af[4], gf[4], uf[4];
            const int pc = ((kk * 4 + q) ^ sw) * 8;   // swizzled phys chunk offset
            #pragma unroll
            for (int m = 0; m < 4; ++m)
                af[m] = *(const s16x8*)&sA[wm * 64 + m * 16 + r16][pc];
            #pragma unroll
            for (int n = 0; n < 4; ++n) {
                gf[n] = *(const s16x8*)&sG[wn * 64 + n * 16 + r16][pc];
                uf[n] = *(const s16x8*)&sU[wn * 64 + n * 16 + r16][pc];
            }
            #pragma unroll
            for (int m = 0; m < 4; ++m)
                #pragma unroll
                for (int n = 0; n < 4; ++n) {
                    accg[m][n] = __builtin_amdgcn_mfma_f32_16x16x32_bf16(af[m], gf[n], accg[m][n], 0, 0, 0);
                    accu[m][n] = __builtin_amdgcn_mfma_f32_16x16x32_bf16(af[m], uf[n], accu[m][n], 0, 0, 0);
                }
        }
    }
    // epilogue: D row = q*4+rr (token), col = r16 (i)
    #pragma unroll
    for (int m = 0; m < 4; ++m) {
        #pragma unroll
        for (int rr = 0; rr < 4; ++rr) {
            int trow = wm * 64 + m * 16 + q * 4 + rr;
            float gate = sGate[trow];
            long base = (long)(t0 + trow) * KDOWN + e * I_DIM;
            #pragma unroll
            for (int n = 0; n < 4; ++n) {
                int icol = i0 + wn * 64 + n * 16 + r16;
                float g = accg[m][n][rr], u = accu[m][n][rr];
                float h = gate * (g / (1.f + __expf(-g))) * u;
                hmid[base + icol] = f2bf(h);
            }
        }
    }
}

// ---------------- down GEMM: out[t][h] += Hmid[t][:] @ WdT[h][:] ----------------
// grid (T/128, H/128, 4 splitK) = (16,8,4); block 256; BK=64; K-chunk 1024
__global__ __launch_bounds__(256) void moe_down_kernel(
    const uint16_t* __restrict__ hmid,  // [2048][4096]
    const uint16_t* __restrict__ wdT,   // [1024][4096]
    float* __restrict__ out) {          // [2048][1024], pre-zeroed
    const int t0 = blockIdx.x * 128;
    const int h0 = blockIdx.y * 128;
    const int k0 = blockIdx.z * 1024;
    __shared__ uint16_t sA[128][64];
    __shared__ uint16_t sB[128][64];
    const int tid  = threadIdx.x;
    const int lane = tid & 63;
    const int wave = tid >> 6;
    const int wm = wave >> 1, wn = wave & 1;

    const int srow = wave * 32 + (lane >> 3);
    const int scol = ((lane & 7) ^ (srow & 7)) * 8;
    const uint16_t* ga = hmid + (long)(t0 + srow) * KDOWN + scol;
    const uint16_t* gb = wdT  + (long)(h0 + srow) * KDOWN + scol;

    f32x4 acc[4][4] = {};
    const int q = lane >> 4, r16 = lane & 15;
    const int sw = r16 & 7;

    for (int kb = k0; kb < k0 + 1024; kb += 64) {
        __syncthreads();
        #pragma unroll
        for (int j = 0; j < 4; ++j) {
            long go = (long)j * 8 * KDOWN + kb;
            gll16(ga + go, &sA[wave * 32 + j * 8][0]);
            gll16(gb + go, &sB[wave * 32 + j * 8][0]);
        }
        __syncthreads();
        #pragma unroll
        for (int kk = 0; kk < 2; ++kk) {
            s16x8 af[4], bf[4];
            const int pc = ((kk * 4 + q) ^ sw) * 8;
            #pragma unroll
            for (int m = 0; m < 4; ++m)
                af[m] = *(const s16x8*)&sA[wm * 64 + m * 16 + r16][pc];
            #pragma unroll
            for (int n = 0; n < 4; ++n)
                bf[n] = *(const s16x8*)&sB[wn * 64 + n * 16 + r16][pc];
            #pragma unroll
            for (int m = 0; m < 4; ++m)
                #pragma unroll
                for (int n = 0; n < 4; ++n)
                    acc[m][n] = __builtin_amdgcn_mfma_f32_16x16x32_bf16(af[m], bf[n], acc[m][n], 0, 0, 0);
        }
    }
    #pragma unroll
    for (int m = 0; m < 4; ++m) {
        #pragma unroll
        for (int rr = 0; rr < 4; ++rr) {
            int t = t0 + wm * 64 + m * 16 + q * 4 + rr;
            #pragma unroll
            for (int n = 0; n < 4; ++n) {
                int h = h0 + wn * 64 + n * 16 + r16;
                atomicAdd(&out[(long)t * H_DIM + h], acc[m][n][rr]);
            }
        }
    }
}

extern "C" void kernel_launch(void* const* d_in, const int* in_sizes, int n_in,
                              void* d_out, int out_size, void* d_ws, size_t ws_size,
                              hipStream_t stream) {
    const float* x    = (const float*)d_in[0];   // [2,1024,1024]
    const float* emb  = (const float*)d_in[1];   // [8,1024]
    const float* thr  = (const float*)d_in[2];   // [8]
    const float* wg   = (const float*)d_in[3];   // [8,1024,512]
    const float* wu   = (const float*)d_in[4];   // [8,1024,512]
    const float* wd   = (const float*)d_in[5];   // [8,512,1024]
    float* out    = (float*)d_out;               // [2048][1024]
    float* scores = out + (size_t)T_TOK * H_DIM; // [2048][8]

    uint8_t* ws = (uint8_t*)d_ws;
    uint16_t* xb   = (uint16_t*)(ws);                         //  4 MB  x bf16
    uint16_t* wgT  = (uint16_t*)(ws + (size_t)4  * 1048576);  //  8 MB  [E][I][H]
    uint16_t* wuT  = (uint16_t*)(ws + (size_t)12 * 1048576);  //  8 MB  [E][I][H]
    uint16_t* wdT  = (uint16_t*)(ws + (size_t)20 * 1048576);  //  8 MB  [H][E*I]
    uint16_t* hmid = (uint16_t*)(ws + (size_t)28 * 1048576);  // 16 MB  [T][E*I]
    float*    gates = (float*)  (ws + (size_t)44 * 1048576);  // 64 KB  [T][E]

    hipMemsetAsync(out, 0, (size_t)T_TOK * H_DIM * sizeof(float), stream);

    cast_x_kernel<<<(T_TOK * H_DIM) / 1024, 256, 0, stream>>>(x, xb);
    transpose_cast_kernel<<<dim3(I_DIM / 32, H_DIM / 32, E_NUM), dim3(32, 8), 0, stream>>>(
        wg, wgT, H_DIM, I_DIM, (long)H_DIM * I_DIM, (long)I_DIM * H_DIM, H_DIM);
    transpose_cast_kernel<<<dim3(I_DIM / 32, H_DIM / 32, E_NUM), dim3(32, 8), 0, stream>>>(
        wu, wuT, H_DIM, I_DIM, (long)H_DIM * I_DIM, (long)I_DIM * H_DIM, H_DIM);
    transpose_cast_kernel<<<dim3(H_DIM / 32, I_DIM / 32, E_NUM), dim3(32, 8), 0, stream>>>(
        wd, wdT, I_DIM, H_DIM, (long)I_DIM * H_DIM, (long)I_DIM, KDOWN);
    routing_kernel<<<T_TOK / 4, 256, 0, stream>>>(x, emb, thr, scores, gates);
    moe_gateup_kernel<<<dim3(T_TOK / 128, I_DIM / 128, E_NUM), 256, 0, stream>>>(
        xb, wgT, wuT, gates, hmid);
    moe_down_kernel<<<dim3(T_TOK / 128, H_DIM / 128, 4), 256, 0, stream>>>(hmid, wdT, out);
}

// Round 3
// 190.049 us; speedup vs baseline: 1.3807x; 1.2136x over previous
//
#include <hip/hip_runtime.h>
#include <hip/hip_bf16.h>
#include <stdint.h>

#define T_TOK 2048
#define H_DIM 1024
#define E_NUM 8
#define I_DIM 512
#define KDOWN (E_NUM * I_DIM) /* 4096 */
#define EPSR 1e-8f

typedef short s16x8 __attribute__((ext_vector_type(8)));
typedef float f32x4 __attribute__((ext_vector_type(4)));

static __device__ __forceinline__ uint16_t f2bf(float f) {
    union { float f; uint32_t i; } v; v.f = f;
    uint32_t lsb = (v.i >> 16) & 1u;
    v.i += 0x7fffu + lsb;                    // round-to-nearest-even
    return (uint16_t)(v.i >> 16);
}

// async global->LDS DMA, 16B/lane; LDS dest = wave-uniform base + lane*16
static __device__ __forceinline__ void gll16(const void* g, void* l) {
    __builtin_amdgcn_global_load_lds(
        (const __attribute__((address_space(1))) void*)g,
        (__attribute__((address_space(3))) void*)l, 16, 0, 0);
}

// ---------------- cast x (fp32 -> bf16), 4 elems/thread ----------------
__global__ __launch_bounds__(256) void cast_x_kernel(const float* __restrict__ x,
                                                     uint16_t* __restrict__ xb) {
    int i = (blockIdx.x * 256 + threadIdx.x) * 4;
    float4 v = *(const float4*)(x + i);
    ushort4 o;
    o.x = f2bf(v.x); o.y = f2bf(v.y); o.z = f2bf(v.z); o.w = f2bf(v.w);
    *(ushort4*)(xb + i) = o;
}

// ------------- transpose + cast: in[R][C] fp32 -> out[c*stride + r] bf16 -------------
// 64x64 tile; float4 reads, ushort4 writes (128B contiguous per 16 lanes)
__global__ __launch_bounds__(256) void transpose_cast_kernel(
    const float* __restrict__ in, uint16_t* __restrict__ out,
    int C, long in_batch, long out_batch, int out_stride) {
    __shared__ float tile[64][68];
    const float* src = in + (long)blockIdx.z * in_batch;
    uint16_t* dst = out + (long)blockIdx.z * out_batch;
    const int r0 = blockIdx.y * 64, c0 = blockIdx.x * 64;
    const int tid = threadIdx.x;
    const int g16 = tid >> 4, l16 = (tid & 15) * 4;
    #pragma unroll
    for (int it = 0; it < 4; ++it) {
        int r = it * 16 + g16;
        *(float4*)&tile[r][l16] = *(const float4*)(src + (long)(r0 + r) * C + c0 + l16);
    }
    __syncthreads();
    #pragma unroll
    for (int it = 0; it < 4; ++it) {
        int oc = it * 16 + g16;       // output row = input column
        ushort4 o;
        o.x = f2bf(tile[l16 + 0][oc]);
        o.y = f2bf(tile[l16 + 1][oc]);
        o.z = f2bf(tile[l16 + 2][oc]);
        o.w = f2bf(tile[l16 + 3][oc]);
        *(ushort4*)(dst + (long)(c0 + oc) * out_stride + r0 + l16) = o;
    }
}

// ---------------- routing: cosine scores + masked softmax gates ----------------
__global__ __launch_bounds__(256) void routing_kernel(
    const float* __restrict__ x, const float* __restrict__ emb,
    const float* __restrict__ thr, float* __restrict__ scores_out,
    float* __restrict__ gates) {
    __shared__ float semb[E_NUM * H_DIM];
    __shared__ float senorm[E_NUM];
    const int tid = threadIdx.x;
    const int lane = tid & 63;
    const int wave = tid >> 6;
    for (int i = tid; i < E_NUM * H_DIM; i += 256) semb[i] = emb[i];
    __syncthreads();
    for (int e = wave; e < E_NUM; e += 4) {
        float s = 0.f;
        #pragma unroll
        for (int c = 0; c < 16; ++c) { float v = semb[e * H_DIM + lane + 64 * c]; s += v * v; }
        #pragma unroll
        for (int off = 32; off; off >>= 1) s += __shfl_xor(s, off);
        if (lane == 0) senorm[e] = fmaxf(sqrtf(s), EPSR);
    }
    __syncthreads();
    const int t = blockIdx.x * 4 + wave;
    const float* xt = x + (long)t * H_DIM;
    float nrm = 0.f, dot[E_NUM];
    #pragma unroll
    for (int e = 0; e < E_NUM; ++e) dot[e] = 0.f;
    #pragma unroll
    for (int c = 0; c < 16; ++c) {
        float v = xt[lane + 64 * c];
        nrm += v * v;
        #pragma unroll
        for (int e = 0; e < E_NUM; ++e) dot[e] += v * semb[e * H_DIM + lane + 64 * c];
    }
    #pragma unroll
    for (int off = 32; off; off >>= 1) {
        nrm += __shfl_xor(nrm, off);
        #pragma unroll
        for (int e = 0; e < E_NUM; ++e) dot[e] += __shfl_xor(dot[e], off);
    }
    float xn = fmaxf(sqrtf(nrm), EPSR);
    float sc[E_NUM], sel[E_NUM];
    float msel = -1e30f, mall = -1e30f;
    int nsel = 0, arg = 0;
    #pragma unroll
    for (int e = 0; e < E_NUM; ++e) {
        sc[e] = dot[e] / (xn * senorm[e]);
        float d = sc[e] - thr[e];
        sel[e] = (d > 0.f) ? 1.f : 0.f;                 // silu(d) > 0  <=>  d > 0
        if (d > 0.f) { nsel++; msel = fmaxf(msel, sc[e]); }
        if (sc[e] > mall) { mall = sc[e]; arg = e; }
    }
    float w[E_NUM], den = 0.f;
    #pragma unroll
    for (int e = 0; e < E_NUM; ++e) { w[e] = (sel[e] > 0.f) ? __expf(sc[e] - msel) : 0.f; den += w[e]; }
    if (lane == 0) {
        #pragma unroll
        for (int e = 0; e < E_NUM; ++e) {
            scores_out[t * E_NUM + e] = sc[e];
            gates[t * E_NUM + e] = (nsel > 0) ? (w[e] / den) : ((e == arg) ? 1.f : 0.f);
        }
    }
}

// ---------------- gate/up GEMM + silu*up*gate -> Hmid bf16 ----------------
// grid (T/128, I/64, E) = (16,8,8)=1024 blocks; 256 thr (2x2 waves, wave-tile 64x32)
// LDS 33KB -> 4 blocks/CU. XOR-swizzled chunk layout (conflict-free, DMA-compatible).
__global__ __launch_bounds__(256, 4) void moe_gateup_kernel(
    const uint16_t* __restrict__ xb,    // [2048][1024]
    const uint16_t* __restrict__ wgT,   // [8][512][1024]
    const uint16_t* __restrict__ wuT,   // [8][512][1024]
    const float* __restrict__ gates,    // [2048][8]
    uint16_t* __restrict__ hmid) {      // [2048][4096] = [t][e*512+i]
    const int e  = blockIdx.z;
    const int t0 = blockIdx.x * 128;
    const int i0 = blockIdx.y * 64;
    __shared__ uint16_t sA[128][64];
    __shared__ uint16_t sG[64][64];
    __shared__ uint16_t sU[64][64];
    __shared__ float sGate[128];
    const int tid  = threadIdx.x;
    const int lane = tid & 63;
    const int wave = tid >> 6;
    const int wm = wave >> 1, wn = wave & 1;
    if (tid < 128) sGate[tid] = gates[(t0 + tid) * E_NUM + e];

    const int srowA = wave * 32 + (lane >> 3);
    const int scA   = ((lane & 7) ^ (srowA & 7)) * 8;
    const int srowG = wave * 16 + (lane >> 3);
    const int scG   = ((lane & 7) ^ (srowG & 7)) * 8;
    const uint16_t* ga = xb  + (long)(t0 + srowA) * H_DIM + scA;
    const uint16_t* gg = wgT + ((long)e * I_DIM + i0 + srowG) * H_DIM + scG;
    const uint16_t* gu = wuT + ((long)e * I_DIM + i0 + srowG) * H_DIM + scG;

    f32x4 accg[4][2] = {};
    f32x4 accu[4][2] = {};
    const int q = lane >> 4, r16 = lane & 15;
    const int sw = r16 & 7;

    for (int kb = 0; kb < H_DIM; kb += 64) {
        __syncthreads();
        #pragma unroll
        for (int j = 0; j < 4; ++j)
            gll16(ga + (long)j * 8 * H_DIM + kb, &sA[wave * 32 + j * 8][0]);
        #pragma unroll
        for (int j = 0; j < 2; ++j) {
            gll16(gg + (long)j * 8 * H_DIM + kb, &sG[wave * 16 + j * 8][0]);
            gll16(gu + (long)j * 8 * H_DIM + kb, &sU[wave * 16 + j * 8][0]);
        }
        __syncthreads();
        #pragma unroll
        for (int kk = 0; kk < 2; ++kk) {
            s16x8 af[4], gf[2], uf[2];
            const int pc = ((kk * 4 + q) ^ sw) * 8;
            #pragma unroll
            for (int m = 0; m < 4; ++m)
                af[m] = *(const s16x8*)&sA[wm * 64 + m * 16 + r16][pc];
            #pragma unroll
            for (int n = 0; n < 2; ++n) {
                gf[n] = *(const s16x8*)&sG[wn * 32 + n * 16 + r16][pc];
                uf[n] = *(const s16x8*)&sU[wn * 32 + n * 16 + r16][pc];
            }
            #pragma unroll
            for (int m = 0; m < 4; ++m)
                #pragma unroll
                for (int n = 0; n < 2; ++n) {
                    accg[m][n] = __builtin_amdgcn_mfma_f32_16x16x32_bf16(af[m], gf[n], accg[m][n], 0, 0, 0);
                    accu[m][n] = __builtin_amdgcn_mfma_f32_16x16x32_bf16(af[m], uf[n], accu[m][n], 0, 0, 0);
                }
        }
    }
    #pragma unroll
    for (int m = 0; m < 4; ++m) {
        #pragma unroll
        for (int rr = 0; rr < 4; ++rr) {
            int trow = wm * 64 + m * 16 + q * 4 + rr;
            float gate = sGate[trow];
            long base = (long)(t0 + trow) * KDOWN + e * I_DIM + i0;
            #pragma unroll
            for (int n = 0; n < 2; ++n) {
                float g = accg[m][n][rr], u = accu[m][n][rr];
                float h = gate * (g / (1.f + __expf(-g))) * u;
                hmid[base + wn * 32 + n * 16 + r16] = f2bf(h);
            }
        }
    }
}

// ---------------- down GEMM: split-K=3; kz0 -> out, kz1/2 -> fp32 partials ----------------
// grid (T/128, H/64, 3) = (16,16,3)=768 blocks; tile 128x64; BK=64; no atomics
__global__ __launch_bounds__(256, 4) void moe_down_kernel(
    const uint16_t* __restrict__ hmid,  // [2048][4096]
    const uint16_t* __restrict__ wdT,   // [1024][4096]
    float* __restrict__ out,            // [2048][1024]
    float* __restrict__ parts) {        // [2][2048][1024]
    const int t0 = blockIdx.x * 128;
    const int h0 = blockIdx.y * 64;
    const int kz = blockIdx.z;
    const int kst  = kz ? kz * 1344 + 64 : 0;
    const int kend = (kz + 1) * 1344 + 64;
    __shared__ uint16_t sA[128][64];
    __shared__ uint16_t sB[64][64];
    const int tid  = threadIdx.x;
    const int lane = tid & 63;
    const int wave = tid >> 6;
    const int wm = wave >> 1, wn = wave & 1;

    const int srowA = wave * 32 + (lane >> 3);
    const int scA   = ((lane & 7) ^ (srowA & 7)) * 8;
    const int srowB = wave * 16 + (lane >> 3);
    const int scB   = ((lane & 7) ^ (srowB & 7)) * 8;
    const uint16_t* ga = hmid + (long)(t0 + srowA) * KDOWN + scA;
    const uint16_t* gb = wdT  + (long)(h0 + srowB) * KDOWN + scB;

    f32x4 acc[4][2] = {};
    const int q = lane >> 4, r16 = lane & 15;
    const int sw = r16 & 7;

    for (int kb = kst; kb < kend; kb += 64) {
        __syncthreads();
        #pragma unroll
        for (int j = 0; j < 4; ++j)
            gll16(ga + (long)j * 8 * KDOWN + kb, &sA[wave * 32 + j * 8][0]);
        #pragma unroll
        for (int j = 0; j < 2; ++j)
            gll16(gb + (long)j * 8 * KDOWN + kb, &sB[wave * 16 + j * 8][0]);
        __syncthreads();
        #pragma unroll
        for (int kk = 0; kk < 2; ++kk) {
            s16x8 af[4], bf[2];
            const int pc = ((kk * 4 + q) ^ sw) * 8;
            #pragma unroll
            for (int m = 0; m < 4; ++m)
                af[m] = *(const s16x8*)&sA[wm * 64 + m * 16 + r16][pc];
            #pragma unroll
            for (int n = 0; n < 2; ++n)
                bf[n] = *(const s16x8*)&sB[wn * 32 + n * 16 + r16][pc];
            #pragma unroll
            for (int m = 0; m < 4; ++m)
                #pragma unroll
                for (int n = 0; n < 2; ++n)
                    acc[m][n] = __builtin_amdgcn_mfma_f32_16x16x32_bf16(af[m], bf[n], acc[m][n], 0, 0, 0);
        }
    }
    float* dst = (kz == 0) ? out : (parts + (long)(kz - 1) * T_TOK * H_DIM);
    #pragma unroll
    for (int m = 0; m < 4; ++m) {
        #pragma unroll
        for (int rr = 0; rr < 4; ++rr) {
            int t = t0 + wm * 64 + m * 16 + q * 4 + rr;
            #pragma unroll
            for (int n = 0; n < 2; ++n)
                dst[(long)t * H_DIM + h0 + wn * 32 + n * 16 + r16] = acc[m][n][rr];
        }
    }
}

// ---------------- reduce: out += part0 + part1 ----------------
__global__ __launch_bounds__(256) void reduce_kernel(float* __restrict__ out,
                                                     const float* __restrict__ parts) {
    long i = ((long)blockIdx.x * 256 + threadIdx.x) * 4;
    float4 a = *(const float4*)(out + i);
    float4 b = *(const float4*)(parts + i);
    float4 c = *(const float4*)(parts + (long)T_TOK * H_DIM + i);
    a.x += b.x + c.x; a.y += b.y + c.y; a.z += b.z + c.z; a.w += b.w + c.w;
    *(float4*)(out + i) = a;
}

extern "C" void kernel_launch(void* const* d_in, const int* in_sizes, int n_in,
                              void* d_out, int out_size, void* d_ws, size_t ws_size,
                              hipStream_t stream) {
    const float* x    = (const float*)d_in[0];   // [2,1024,1024]
    const float* emb  = (const float*)d_in[1];   // [8,1024]
    const float* thr  = (const float*)d_in[2];   // [8]
    const float* wg   = (const float*)d_in[3];   // [8,1024,512]
    const float* wu   = (const float*)d_in[4];   // [8,1024,512]
    const float* wd   = (const float*)d_in[5];   // [8,512,1024]
    float* out    = (float*)d_out;               // [2048][1024]
    float* scores = out + (size_t)T_TOK * H_DIM; // [2048][8]

    uint8_t* ws = (uint8_t*)d_ws;
    uint16_t* xb   = (uint16_t*)(ws);                         //  4 MB  x bf16
    uint16_t* wgT  = (uint16_t*)(ws + (size_t)4  * 1048576);  //  8 MB  [E][I][H]
    uint16_t* wuT  = (uint16_t*)(ws + (size_t)12 * 1048576);  //  8 MB  [E][I][H]
    uint16_t* wdT  = (uint16_t*)(ws + (size_t)20 * 1048576);  //  8 MB  [H][E*I]
    uint16_t* hmid = (uint16_t*)(ws + (size_t)28 * 1048576);  // 16 MB  [T][E*I]
    float*    gates = (float*)  (ws + (size_t)44 * 1048576);  // 64 KB  [T][E]
    // down-GEMM partials (16 MB) reuse xb/wgT region — dead after gateup
    float*    parts = (float*)ws;

    cast_x_kernel<<<(T_TOK * H_DIM) / 1024, 256, 0, stream>>>(x, xb);
    // Wg [H][I] -> wgT[e][i][h]
    transpose_cast_kernel<<<dim3(I_DIM / 64, H_DIM / 64, E_NUM), 256, 0, stream>>>(
        wg, wgT, I_DIM, (long)H_DIM * I_DIM, (long)I_DIM * H_DIM, H_DIM);
    transpose_cast_kernel<<<dim3(I_DIM / 64, H_DIM / 64, E_NUM), 256, 0, stream>>>(
        wu, wuT, I_DIM, (long)H_DIM * I_DIM, (long)I_DIM * H_DIM, H_DIM);
    // Wd [I][H] -> wdT[h][e*512+i]
    transpose_cast_kernel<<<dim3(H_DIM / 64, I_DIM / 64, E_NUM), 256, 0, stream>>>(
        wd, wdT, H_DIM, (long)I_DIM * H_DIM, (long)I_DIM, KDOWN);
    routing_kernel<<<T_TOK / 4, 256, 0, stream>>>(x, emb, thr, scores, gates);
    moe_gateup_kernel<<<dim3(T_TOK / 128, I_DIM / 64, E_NUM), 256, 0, stream>>>(
        xb, wgT, wuT, gates, hmid);
    moe_down_kernel<<<dim3(T_TOK / 128, H_DIM / 64, 3), 256, 0, stream>>>(hmid, wdT, out, parts);
    reduce_kernel<<<(T_TOK * H_DIM) / 1024, 256, 0, stream>>>(out, parts);
}